// Round 9
// baseline (273.876 us; speedup 1.0000x reference)
//
#include <hip/hip_runtime.h>
#include <hip/hip_bf16.h>

#define NTOK 512
#define TJ 32
#define EPSF 1e-5f

// One block per output row i. 256 threads.
// ACC[m][h]: m 0..15 Q00 (pairs h00), 16..31 P10 (h10), 32..79 R01 (h01), 80..127 U11 (h11).
__global__ __launch_bounds__(256, 2) void tfn_kernel(
    const float* __restrict__ f0,  const float* __restrict__ f1,
    const float* __restrict__ rbf, const float* __restrict__ rhat,
    const void*  __restrict__ maskp,
    const float* __restrict__ w00a, const float* __restrict__ b00a,
    const float* __restrict__ w00b, const float* __restrict__ b00b,
    const float* __restrict__ w10a, const float* __restrict__ b10a,
    const float* __restrict__ w10b, const float* __restrict__ b10b,
    const float* __restrict__ w01a, const float* __restrict__ b01a,
    const float* __restrict__ w01b, const float* __restrict__ b01b,
    const float* __restrict__ w11a, const float* __restrict__ b11a,
    const float* __restrict__ w11b, const float* __restrict__ b11b,
    const float* __restrict__ g0, const float* __restrict__ be0,
    const float* __restrict__ g1, const float* __restrict__ be1,
    float* __restrict__ out)
{
  const int i = blockIdx.x;
  const int t = threadIdx.x;

  __shared__ float wa_s[128][17];   // stacked wa00|wa10|wa01|wa11
  __shared__ float ba_s[128];
  __shared__ float rbft[TJ][17];
  __shared__ float rhatt[TJ][4];
  __shared__ float maskt[TJ];
  __shared__ float f0t[TJ][17];
  __shared__ float f1t[TJ][49];     // [jj][k*3+x]
  __shared__ float dott[TJ][17];
  __shared__ __align__(16) float hbuf[TJ][132];   // [jj][128 h-rows]
  __shared__ __align__(16) float lhsbuf[TJ][132]; // [jj][128 m-cols]
  __shared__ float ACCs[128][33];
  __shared__ float biasacc[128];
  __shared__ float m00s[16], m10s[16];
  __shared__ float p01[48], p11[48];
  __shared__ float rawb[16][3];
  __shared__ float norms_s[16];
  __shared__ int mask_mode;  // 0 = 1-byte bool, 1 = 4-byte (int/float: nonzero test)

  // ---- detect mask element width (deterministic; same on every block) ----
  if (t == 0) {
    const unsigned char* mb = (const unsigned char*)maskp;
    int nz = 0; int big = 0;
    for (int k = 0; k < 256; ++k) { nz += (mb[k] != 0); big |= (mb[k] > 1); }
    mask_mode = (big || nz <= 80) ? 1 : 0;
  }

  // ---- load stacked first-layer weights once per block ----
  for (int idx = t; idx < 2048; idx += 256) {
    int row = idx >> 4, r = idx & 15;
    const float* src = (row < 32) ? w00a : (row < 64) ? w10a : (row < 96) ? w01a : w11a;
    wa_s[row][r] = src[(row & 31) * 16 + r];
  }
  if (t < 128) {
    int row = t;
    const float* src = (row < 32) ? b00a : (row < 64) ? b10a : (row < 96) ? b01a : b11a;
    ba_s[row] = src[row & 31];
  }

  const int th = t & 7;        // h-block 0..7
  const int tm = t >> 3;       // m-block 0..31
  const int m0 = tm * 4;
  const int hb = (m0 < 16) ? 0 : (m0 < 32) ? 8 : (m0 < 80) ? 16 : 24; // float4 units into hbuf row
  float acc[4][4] = {{0.f}};
  float biasr[4] = {0.f, 0.f, 0.f, 0.f};

  for (int tile = 0; tile < NTOK / TJ; ++tile) {
    __syncthreads();  // staging buffers free (also covers wa_s/mask_mode on tile 0)
    const int j0 = tile * TJ;
    // ---- stage tile inputs ----
    for (int idx = t; idx < 512; idx += 256) {
      int jj = idx >> 4, r = idx & 15;
      rbft[jj][r] = rbf[((size_t)i * NTOK + j0 + jj) * 16 + r];
      f0t[jj][r]  = f0[(j0 + jj) * 16 + r];
    }
    for (int idx = t; idx < 1536; idx += 256) {
      int jj = idx / 48, e = idx % 48;
      f1t[jj][e] = f1[(j0 + jj) * 48 + e];
    }
    if (t < 96) {
      int jj = t / 3, x = t % 3;
      rhatt[jj][x] = rhat[((size_t)i * NTOK + j0 + jj) * 3 + x];
    }
    if (t < TJ) {
      size_t idx = (size_t)i * NTOK + j0 + t;
      bool mv = (mask_mode == 0) ? (((const unsigned char*)maskp)[idx] != 0)
                                 : (((const int*)maskp)[idx] != 0);
      maskt[t] = mv ? 1.0f : 0.0f;
    }
    __syncthreads();
    // ---- dot[jj][c] = r_hat . f1[j,c,:] ----
    for (int idx = t; idx < 512; idx += 256) {
      int jj = idx >> 4, c = idx & 15;
      dott[jj][c] = rhatt[jj][0] * f1t[jj][c * 3 + 0]
                  + rhatt[jj][1] * f1t[jj][c * 3 + 1]
                  + rhatt[jj][2] * f1t[jj][c * 3 + 2];
    }
    __syncthreads();
    // ---- h (4 MLP first layers + silu) and lhs ----
    {
      const int jj = t & 31, part = t >> 5;
      const int r0 = part * 16;
      float rb[16];
      #pragma unroll
      for (int r = 0; r < 16; ++r) rb[r] = rbft[jj][r];
      #pragma unroll
      for (int u = 0; u < 16; ++u) {
        int row = r0 + u;
        float p = ba_s[row];
        #pragma unroll
        for (int r = 0; r < 16; ++r) p += wa_s[row][r] * rb[r];
        hbuf[jj][row] = p / (1.0f + __expf(-p));  // silu
      }
      const float mk = maskt[jj];
      #pragma unroll
      for (int u = 0; u < 16; ++u) {
        int m = r0 + u;
        float v;
        if (m < 16)       v = mk * f0t[jj][m];
        else if (m < 32)  v = mk * dott[jj][m - 16];
        else if (m < 80)  { int mm = m - 32; v = mk * f0t[jj][mm / 3] * rhatt[jj][mm % 3]; }
        else              { int mm = m - 80; v = mk * f1t[jj][mm]; }
        lhsbuf[jj][m] = v;
      }
    }
    __syncthreads();
    // ---- outer-product accumulate (register-blocked 4x4) ----
    #pragma unroll 8
    for (int jj = 0; jj < TJ; ++jj) {
      const float4 L = *(const float4*)&lhsbuf[jj][m0];
      const float4 H = *(const float4*)&hbuf[jj][(hb + th) * 4];
      acc[0][0] += L.x * H.x; acc[0][1] += L.x * H.y; acc[0][2] += L.x * H.z; acc[0][3] += L.x * H.w;
      acc[1][0] += L.y * H.x; acc[1][1] += L.y * H.y; acc[1][2] += L.y * H.z; acc[1][3] += L.y * H.w;
      acc[2][0] += L.z * H.x; acc[2][1] += L.z * H.y; acc[2][2] += L.z * H.z; acc[2][3] += L.z * H.w;
      acc[3][0] += L.w * H.x; acc[3][1] += L.w * H.y; acc[3][2] += L.w * H.z; acc[3][3] += L.w * H.w;
      biasr[0] += L.x; biasr[1] += L.y; biasr[2] += L.z; biasr[3] += L.w;  // only th==0 used
    }
  }

  __syncthreads();
  #pragma unroll
  for (int a = 0; a < 4; ++a)
    #pragma unroll
    for (int b = 0; b < 4; ++b)
      ACCs[m0 + a][th * 4 + b] = acc[a][b];
  if (th == 0) {
    #pragma unroll
    for (int a = 0; a < 4; ++a) biasacc[m0 + a] = biasr[a];
  }
  __syncthreads();

  // ---- epilogue: contract with second-layer weights ----
  if (t < 16) {
    int o = t; float s = 0.f;
    for (int d = 0; d < 16; ++d) {
      const float* wrow = w00b + (d * 16 + o) * 32;
      float ss = 0.f;
      #pragma unroll
      for (int h = 0; h < 32; ++h) ss += wrow[h] * ACCs[d][h];
      s += ss + b00b[d * 16 + o] * biasacc[d];
    }
    m00s[o] = s;
  } else if (t < 32) {
    int o = t - 16; float s = 0.f;
    for (int c = 0; c < 16; ++c) {
      const float* wrow = w10b + (c * 16 + o) * 32;
      float ss = 0.f;
      #pragma unroll
      for (int h = 0; h < 32; ++h) ss += wrow[h] * ACCs[16 + c][h];
      s += ss + b10b[c * 16 + o] * biasacc[16 + c];
    }
    m10s[o] = s;
  } else if (t < 80) {
    int idx = t - 32; int g = idx / 3, x = idx % 3; float s = 0.f;
    for (int f = 0; f < 16; ++f) {
      const float* wrow = w01b + (f * 16 + g) * 32;
      int m = 32 + f * 3 + x;
      float ss = 0.f;
      #pragma unroll
      for (int h = 0; h < 32; ++h) ss += wrow[h] * ACCs[m][h];
      s += ss + b01b[f * 16 + g] * biasacc[m];
    }
    p01[idx] = s;
  } else if (t < 128) {
    int idx = t - 80; int g = idx / 3, x = idx % 3; float s = 0.f;
    for (int k = 0; k < 16; ++k) {
      const float* wrow = w11b + (k * 16 + g) * 32;
      int m = 80 + k * 3 + x;
      float ss = 0.f;
      #pragma unroll
      for (int h = 0; h < 32; ++h) ss += wrow[h] * ACCs[m][h];
      s += ss + b11b[k * 16 + g] * biasacc[m];
    }
    p11[idx] = s;
  }
  __syncthreads();

  if (t < 16) {
    // new_f0 = LN(msg00+msg10)*g0+be0  (fp32 output)
    float v = m00s[t] + m10s[t];
    float mu = 0.f;
    #pragma unroll
    for (int k = 0; k < 16; ++k) mu += m00s[k] + m10s[k];
    mu *= (1.f / 16.f);
    float var = 0.f;
    #pragma unroll
    for (int k = 0; k < 16; ++k) { float d = m00s[k] + m10s[k] - mu; var += d * d; }
    var *= (1.f / 16.f);
    out[(size_t)i * 16 + t] = (v - mu) * rsqrtf(var + EPSF) * g0[t] + be0[t];
    // f1 raw + norms
    float r0v = p01[t * 3 + 0] + p11[t * 3 + 0];
    float r1v = p01[t * 3 + 1] + p11[t * 3 + 1];
    float r2v = p01[t * 3 + 2] + p11[t * 3 + 2];
    rawb[t][0] = r0v; rawb[t][1] = r1v; rawb[t][2] = r2v;
    float nrm = sqrtf(r0v * r0v + r1v * r1v + r2v * r2v);
    norms_s[t] = fmaxf(nrm, 1e-8f);
  }
  __syncthreads();
  if (t < 16) {
    int g = t;
    float mu = 0.f;
    #pragma unroll
    for (int k = 0; k < 16; ++k) mu += norms_s[k];
    mu *= (1.f / 16.f);
    float var = 0.f;
    #pragma unroll
    for (int k = 0; k < 16; ++k) { float d = norms_s[k] - mu; var += d * d; }
    var *= (1.f / 16.f);
    float ln = (norms_s[g] - mu) * rsqrtf(var + EPSF) * g1[g] + be1[g];
    float scale = ln / norms_s[g];
    size_t base = (size_t)NTOK * 16 + (size_t)i * 48 + g * 3;
    out[base + 0] = rawb[g][0] * scale;
    out[base + 1] = rawb[g][1] * scale;
    out[base + 2] = rawb[g][2] * scale;
  }
}

extern "C" void kernel_launch(void* const* d_in, const int* in_sizes, int n_in,
                              void* d_out, int out_size, void* d_ws, size_t ws_size,
                              hipStream_t stream) {
  // ---- identify inputs by size signature (robust to pos being absent) ----
  int idx_f0 = -1, idx_f1 = -1, idx_rbf = -1, idx_rhat = -1, idx_mask = -1;
  int wa_i[4], ba_i[4], wb_i[4], bb_i[4], g_i[4];
  int nwa = 0, nba = 0, nwb = 0, nbb = 0, ng = 0;
  for (int k = 0; k < n_in; ++k) {
    const int s = in_sizes[k];
    if      (s == 4194304) idx_rbf  = k;
    else if (s == 786432)  idx_rhat = k;
    else if (s == 262144)  idx_mask = k;
    else if (s == 24576)   idx_f1   = k;
    else if (s == 8192)    { if (idx_f0 < 0) idx_f0 = k; else if (nwb < 4) wb_i[nwb++] = k; }
    else if (s == 512)     { if (nwa < 4) wa_i[nwa++] = k; }
    else if (s == 32)      { if (nba < 4) ba_i[nba++] = k; }
    else if (s == 256)     { if (nbb < 4) bb_i[nbb++] = k; }
    else if (s == 16)      { if (ng  < 4) g_i[ng++]  = k; }
  }
  const bool ok = idx_f0 >= 0 && idx_f1 >= 0 && idx_rbf >= 0 && idx_rhat >= 0 &&
                  idx_mask >= 0 && nwa == 4 && nba == 4 && nwb == 4 && nbb == 4 && ng == 4;
  if (!ok) {
    idx_f0 = 1; idx_f1 = 2; idx_rbf = 3; idx_rhat = 4; idx_mask = 5;
    for (int q = 0; q < 4; ++q) {
      wa_i[q] = 6 + q * 4; ba_i[q] = 7 + q * 4; wb_i[q] = 8 + q * 4; bb_i[q] = 9 + q * 4;
      g_i[q] = 22 + q;
    }
  }
  tfn_kernel<<<512, 256, 0, stream>>>(
      (const float*)d_in[idx_f0],  (const float*)d_in[idx_f1],
      (const float*)d_in[idx_rbf], (const float*)d_in[idx_rhat],
      (const void*)d_in[idx_mask],
      (const float*)d_in[wa_i[0]], (const float*)d_in[ba_i[0]],
      (const float*)d_in[wb_i[0]], (const float*)d_in[bb_i[0]],
      (const float*)d_in[wa_i[1]], (const float*)d_in[ba_i[1]],
      (const float*)d_in[wb_i[1]], (const float*)d_in[bb_i[1]],
      (const float*)d_in[wa_i[2]], (const float*)d_in[ba_i[2]],
      (const float*)d_in[wb_i[2]], (const float*)d_in[bb_i[2]],
      (const float*)d_in[wa_i[3]], (const float*)d_in[ba_i[3]],
      (const float*)d_in[wb_i[3]], (const float*)d_in[bb_i[3]],
      (const float*)d_in[g_i[0]], (const float*)d_in[g_i[1]],
      (const float*)d_in[g_i[2]], (const float*)d_in[g_i[3]],
      (float*)d_out);
}

// Round 10
// 259.999 us; speedup vs baseline: 1.0534x; 1.0534x over previous
//
#include <hip/hip_runtime.h>

#define NTOK 512
#define TJ 16
#define NTILE (NTOK/TJ)
#define EPSF 1e-5f

// LDS float-offsets. Persistent: wa/ba. Staging+work region S0.. overlaid by epilogue ACC.
#define OFF_WA   0              // [128][20] stride-20: b128-aligned, bank-disjoint across parts
#define OFF_BA   2560           // [128]
#define S0       2688
#define OFF_RBF  (S0)           // [16][20]
#define OFF_F0   (S0+320)       // [16][20]
#define OFF_F1   (S0+640)       // [16][52]
#define OFF_RH   (S0+1472)      // [48] flat jj*3+x
#define OFF_MK   (S0+1520)      // [16]
#define OFF_H    (S0+1536)      // [16][132]
#define OFF_LHS  (S0+3648)      // [16][132]
// epilogue overlay (staging region dead after last acc barrier)
#define OFF_ACC  (S0)           // [128][36]
#define OFF_BIAS (S0+4608)      // [128]
#define OFF_M00  (S0+4736)
#define OFF_M10  (S0+4752)
#define OFF_P01  (S0+4768)
#define OFF_P11  (S0+4816)
#define OFF_RAW  (S0+4864)
#define OFF_NRM  (S0+4912)
#define LDS_FLOATS (S0+5760)    // 8448 floats = 33.8 KB -> 4 blocks/CU

__global__ __launch_bounds__(256, 4) void tfn_kernel(
    const float* __restrict__ f0,  const float* __restrict__ f1,
    const float* __restrict__ rbf, const float* __restrict__ rhat,
    const int*  __restrict__ mask,
    const float* __restrict__ w00a, const float* __restrict__ b00a,
    const float* __restrict__ w00b, const float* __restrict__ b00b,
    const float* __restrict__ w10a, const float* __restrict__ b10a,
    const float* __restrict__ w10b, const float* __restrict__ b10b,
    const float* __restrict__ w01a, const float* __restrict__ b01a,
    const float* __restrict__ w01b, const float* __restrict__ b01b,
    const float* __restrict__ w11a, const float* __restrict__ b11a,
    const float* __restrict__ w11b, const float* __restrict__ b11b,
    const float* __restrict__ g0, const float* __restrict__ be0,
    const float* __restrict__ g1, const float* __restrict__ be1,
    float* __restrict__ out)
{
  __shared__ float lds[LDS_FLOATS];
  const int i = blockIdx.x;
  const int t = threadIdx.x;

  // ---- persistent: stacked first-layer weights, stride 20 ----
  for (int q = t; q < 512; q += 256) {
    int row = q >> 2, e = q & 3;
    const float* src = (row < 32) ? w00a : (row < 64) ? w10a : (row < 96) ? w01a : w11a;
    float4 v = *(const float4*)(src + (row & 31) * 16 + e * 4);
    *(float4*)&lds[OFF_WA + row * 20 + e * 4] = v;
  }
  if (t < 128) {
    const float* src = (t < 32) ? b00a : (t < 64) ? b10a : (t < 96) ? b01a : b11a;
    lds[OFF_BA + t] = src[t & 31];
  }

  // ---- per-thread staging descriptors (2 float4 slots per thread) ----
  const float* gp0; int gs0, lo0, im0;
  const float* gp1 = nullptr; int gs1 = 0, lo1 = 0, im1 = 0;
  const bool act1 = (t < 80);
  {
    int q = t;
    { // slot 0 (q < 336 always)
      if (q < 64)       { int jj=q>>2, e=q&3; gp0 = rbf + ((size_t)i*NTOK + jj)*16 + e*4; gs0 = TJ*16; lo0 = OFF_RBF + jj*20 + e*4; im0 = 0; }
      else if (q < 128) { int p=q-64, jj=p>>2, e=p&3; gp0 = f0 + jj*16 + e*4; gs0 = TJ*16; lo0 = OFF_F0 + jj*20 + e*4; im0 = 0; }
      else              { int p=q-128, jj=p/12, e=p%12; gp0 = f1 + jj*48 + e*4; gs0 = TJ*48; lo0 = OFF_F1 + jj*52 + e*4; im0 = 0; }
    }
    q = t + 256;
    if (act1) { // slot 1: q in [256,336)
      if (q < 320)      { int p=q-128, jj=p/12, e=p%12; gp1 = f1 + jj*48 + e*4; gs1 = TJ*48; lo1 = OFF_F1 + jj*52 + e*4; im1 = 0; }
      else if (q < 332) { int e=q-320; gp1 = rhat + (size_t)i*NTOK*3 + e*4; gs1 = TJ*3; lo1 = OFF_RH + e*4; im1 = 0; }
      else              { int e=q-332; gp1 = (const float*)(mask + (size_t)i*NTOK + e*4); gs1 = TJ; lo1 = OFF_MK + e*4; im1 = 1; }
    }
  }

  // ---- h-phase ids: 2 jj per thread, 4 rows ----
  const int jg   = t & 7;          // jjA=jg, jjB=jg+8
  const int part = t >> 3;         // 0..31; rows = u*32+part
  const int f_u1 = part / 3,        x_u1 = part % 3;          // u=1 (kind2)
  const int f_u2 = (32 + part) / 3, x_u2 = (32 + part) % 3;   // u=2, part<16 (kind2)
  const int c_u2 = part - 16;                                 // u=2, part>=16 (kind3)
  const int c_u3 = 16 + part;                                 // u=3 (kind3)

  // ---- acc-phase ids: 8m x 4h per lane, j-split across thread halves ----
  const int g2 = t >> 7;           // 0/1: jj in [g2*8, g2*8+8)
  const int l  = t & 127;
  const int mB = l >> 3;           // 0..15: m = mB*8..+8
  const int hB = l & 7;            // 0..7:  h-local = hB*4..+4
  const int qoff = (mB < 2) ? 0 : (mB < 4) ? 32 : (mB < 10) ? 64 : 96;

  float acc[8][4];
  #pragma unroll
  for (int a = 0; a < 8; ++a) { acc[a][0]=0.f; acc[a][1]=0.f; acc[a][2]=0.f; acc[a][3]=0.f; }
  float biasr = 0.f;               // bias for m = mB*8 + hB

  // prime prefetch
  float4 pre0 = *(const float4*)gp0; gp0 += gs0;
  float4 pre1 = make_float4(0,0,0,0);
  if (act1) { pre1 = *(const float4*)gp1; gp1 += gs1; }

  for (int tile = 0; tile < NTILE; ++tile) {
    // ---- stage from regs (staging region free: prior h-phase done) ----
    *(float4*)&lds[lo0] = pre0;            // im0 always 0
    if (act1) {
      if (!im1) *(float4*)&lds[lo1] = pre1;
      else {
        lds[lo1+0] = (__float_as_int(pre1.x) != 0) ? 1.f : 0.f;
        lds[lo1+1] = (__float_as_int(pre1.y) != 0) ? 1.f : 0.f;
        lds[lo1+2] = (__float_as_int(pre1.z) != 0) ? 1.f : 0.f;
        lds[lo1+3] = (__float_as_int(pre1.w) != 0) ? 1.f : 0.f;
      }
    }
    if (tile + 1 < NTILE) {
      pre0 = *(const float4*)gp0; gp0 += gs0;
      if (act1) { pre1 = *(const float4*)gp1; gp1 += gs1; }
    }
    __syncthreads();   // B1: staging visible; hbuf/lhs free (prev acc done before stage-write? acc only reads H/LHS which h-phase rewrites AFTER this barrier)

    // ---- h + lhs ----
    {
      float rbA[16], rbB[16];
      #pragma unroll
      for (int e = 0; e < 4; ++e) {
        float4 va = *(float4*)&lds[OFF_RBF + jg*20 + e*4];
        float4 vb = *(float4*)&lds[OFF_RBF + (jg+8)*20 + e*4];
        rbA[e*4+0]=va.x; rbA[e*4+1]=va.y; rbA[e*4+2]=va.z; rbA[e*4+3]=va.w;
        rbB[e*4+0]=vb.x; rbB[e*4+1]=vb.y; rbB[e*4+2]=vb.z; rbB[e*4+3]=vb.w;
      }
      const float mkA = lds[OFF_MK + jg],      mkB = lds[OFF_MK + jg+8];
      const float rA0 = lds[OFF_RH + jg*3+0],  rA1 = lds[OFF_RH + jg*3+1],  rA2 = lds[OFF_RH + jg*3+2];
      const float rB0 = lds[OFF_RH + (jg+8)*3+0], rB1 = lds[OFF_RH + (jg+8)*3+1], rB2 = lds[OFF_RH + (jg+8)*3+2];
      const float rxA1 = (x_u1==0)?rA0:(x_u1==1)?rA1:rA2;
      const float rxB1 = (x_u1==0)?rB0:(x_u1==1)?rB1:rB2;
      const float rxA2 = (x_u2==0)?rA0:(x_u2==1)?rA1:rA2;
      const float rxB2 = (x_u2==0)?rB0:(x_u2==1)?rB1:rB2;
      #pragma unroll
      for (int u = 0; u < 4; ++u) {
        const int row = u*32 + part;
        float wv[16];
        #pragma unroll
        for (int e = 0; e < 4; ++e) {
          float4 v = *(float4*)&lds[OFF_WA + row*20 + e*4];
          wv[e*4+0]=v.x; wv[e*4+1]=v.y; wv[e*4+2]=v.z; wv[e*4+3]=v.w;
        }
        float pA = lds[OFF_BA + row], pB = pA;
        #pragma unroll
        for (int r = 0; r < 16; ++r) { pA += wv[r]*rbA[r]; pB += wv[r]*rbB[r]; }
        lds[OFF_H + jg*132 + row]     = pA / (1.f + __expf(-pA));
        lds[OFF_H + (jg+8)*132 + row] = pB / (1.f + __expf(-pB));
        float vA, vB;
        if (u == 0) {
          if (part < 16) { vA = mkA * lds[OFF_F0 + jg*20 + part]; vB = mkB * lds[OFF_F0 + (jg+8)*20 + part]; }
          else {
            const int c = part - 16;
            vA = mkA * (rA0*lds[OFF_F1 + jg*52 + c*3] + rA1*lds[OFF_F1 + jg*52 + c*3 + 1] + rA2*lds[OFF_F1 + jg*52 + c*3 + 2]);
            vB = mkB * (rB0*lds[OFF_F1 + (jg+8)*52 + c*3] + rB1*lds[OFF_F1 + (jg+8)*52 + c*3 + 1] + rB2*lds[OFF_F1 + (jg+8)*52 + c*3 + 2]);
          }
        } else if (u == 1) {
          vA = mkA * lds[OFF_F0 + jg*20 + f_u1] * rxA1;
          vB = mkB * lds[OFF_F0 + (jg+8)*20 + f_u1] * rxB1;
        } else if (u == 2) {
          if (part < 16) { vA = mkA * lds[OFF_F0 + jg*20 + f_u2] * rxA2; vB = mkB * lds[OFF_F0 + (jg+8)*20 + f_u2] * rxB2; }
          else           { vA = mkA * lds[OFF_F1 + jg*52 + c_u2]; vB = mkB * lds[OFF_F1 + (jg+8)*52 + c_u2]; }
        } else {
          vA = mkA * lds[OFF_F1 + jg*52 + c_u3]; vB = mkB * lds[OFF_F1 + (jg+8)*52 + c_u3];
        }
        lds[OFF_LHS + jg*132 + row] = vA;
        lds[OFF_LHS + (jg+8)*132 + row] = vB;
      }
    }
    __syncthreads();   // B2: H/LHS visible, staging fully consumed

    // ---- acc: 8m x 4h per lane over group's 8 jj ----
    {
      const int jbase = g2 * 8;
      #pragma unroll
      for (int v = 0; v < 8; ++v) {
        const int jj = jbase + v;
        const float4 L0 = *(float4*)&lds[OFF_LHS + jj*132 + mB*8];
        const float4 L1 = *(float4*)&lds[OFF_LHS + jj*132 + mB*8 + 4];
        const float4 H0 = *(float4*)&lds[OFF_H + jj*132 + qoff + hB*4];
        const float la[8] = {L0.x,L0.y,L0.z,L0.w,L1.x,L1.y,L1.z,L1.w};
        #pragma unroll
        for (int a = 0; a < 8; ++a) {
          acc[a][0] += la[a]*H0.x; acc[a][1] += la[a]*H0.y;
          acc[a][2] += la[a]*H0.z; acc[a][3] += la[a]*H0.w;
        }
        biasr += la[hB];
      }
    }
  }

  // ---- reduce the 2 group-partials into overlaid ACC ----
  __syncthreads();
  if (t < 128) {
    #pragma unroll
    for (int a = 0; a < 8; ++a) {
      float4 w; w.x=acc[a][0]; w.y=acc[a][1]; w.z=acc[a][2]; w.w=acc[a][3];
      *(float4*)&lds[OFF_ACC + (mB*8+a)*36 + hB*4] = w;
    }
    lds[OFF_BIAS + mB*8 + hB] = biasr;
  }
  __syncthreads();
  if (t >= 128) {
    #pragma unroll
    for (int a = 0; a < 8; ++a) {
      float4 o = *(float4*)&lds[OFF_ACC + (mB*8+a)*36 + hB*4];
      o.x += acc[a][0]; o.y += acc[a][1]; o.z += acc[a][2]; o.w += acc[a][3];
      *(float4*)&lds[OFF_ACC + (mB*8+a)*36 + hB*4] = o;
    }
    lds[OFF_BIAS + mB*8 + hB] += biasr;
  }
  __syncthreads();

  // ---- epilogue: contract with second-layer weights ----
  if (t < 16) {
    int o = t; float s = 0.f;
    for (int d = 0; d < 16; ++d) {
      const float* wrow = w00b + (d*16 + o)*32;
      float ss = 0.f;
      #pragma unroll
      for (int h = 0; h < 32; ++h) ss += wrow[h] * lds[OFF_ACC + d*36 + h];
      s += ss + b00b[d*16 + o] * lds[OFF_BIAS + d];
    }
    lds[OFF_M00 + o] = s;
  } else if (t < 32) {
    int o = t - 16; float s = 0.f;
    for (int c = 0; c < 16; ++c) {
      const float* wrow = w10b + (c*16 + o)*32;
      float ss = 0.f;
      #pragma unroll
      for (int h = 0; h < 32; ++h) ss += wrow[h] * lds[OFF_ACC + (16+c)*36 + h];
      s += ss + b10b[c*16 + o] * lds[OFF_BIAS + 16 + c];
    }
    lds[OFF_M10 + o] = s;
  } else if (t < 80) {
    int idx = t - 32, g = idx/3, x = idx%3; float s = 0.f;
    for (int f = 0; f < 16; ++f) {
      const float* wrow = w01b + (f*16 + g)*32;
      int m = 32 + f*3 + x;
      float ss = 0.f;
      #pragma unroll
      for (int h = 0; h < 32; ++h) ss += wrow[h] * lds[OFF_ACC + m*36 + h];
      s += ss + b01b[f*16 + g] * lds[OFF_BIAS + m];
    }
    lds[OFF_P01 + idx] = s;
  } else if (t < 128) {
    int idx = t - 80, g = idx/3, x = idx%3; float s = 0.f;
    for (int k = 0; k < 16; ++k) {
      const float* wrow = w11b + (k*16 + g)*32;
      int m = 80 + k*3 + x;
      float ss = 0.f;
      #pragma unroll
      for (int h = 0; h < 32; ++h) ss += wrow[h] * lds[OFF_ACC + m*36 + h];
      s += ss + b11b[k*16 + g] * lds[OFF_BIAS + m];
    }
    lds[OFF_P11 + idx] = s;
  }
  __syncthreads();

  if (t < 16) {
    float v = lds[OFF_M00 + t] + lds[OFF_M10 + t];
    float mu = 0.f;
    #pragma unroll
    for (int k = 0; k < 16; ++k) mu += lds[OFF_M00 + k] + lds[OFF_M10 + k];
    mu *= (1.f/16.f);
    float var = 0.f;
    #pragma unroll
    for (int k = 0; k < 16; ++k) { float d = lds[OFF_M00 + k] + lds[OFF_M10 + k] - mu; var += d*d; }
    var *= (1.f/16.f);
    out[(size_t)i*16 + t] = (v - mu) * rsqrtf(var + EPSF) * g0[t] + be0[t];
    float r0v = lds[OFF_P01 + t*3+0] + lds[OFF_P11 + t*3+0];
    float r1v = lds[OFF_P01 + t*3+1] + lds[OFF_P11 + t*3+1];
    float r2v = lds[OFF_P01 + t*3+2] + lds[OFF_P11 + t*3+2];
    lds[OFF_RAW + t*3+0] = r0v; lds[OFF_RAW + t*3+1] = r1v; lds[OFF_RAW + t*3+2] = r2v;
    lds[OFF_NRM + t] = fmaxf(sqrtf(r0v*r0v + r1v*r1v + r2v*r2v), 1e-8f);
  }
  __syncthreads();
  if (t < 16) {
    float mu = 0.f;
    #pragma unroll
    for (int k = 0; k < 16; ++k) mu += lds[OFF_NRM + k];
    mu *= (1.f/16.f);
    float var = 0.f;
    #pragma unroll
    for (int k = 0; k < 16; ++k) { float d = lds[OFF_NRM + k] - mu; var += d*d; }
    var *= (1.f/16.f);
    float ln = (lds[OFF_NRM + t] - mu) * rsqrtf(var + EPSF) * g1[t] + be1[t];
    float scale = ln / lds[OFF_NRM + t];
    size_t base = (size_t)NTOK*16 + (size_t)i*48 + t*3;
    out[base+0] = lds[OFF_RAW + t*3+0] * scale;
    out[base+1] = lds[OFF_RAW + t*3+1] * scale;
    out[base+2] = lds[OFF_RAW + t*3+2] * scale;
  }
}

extern "C" void kernel_launch(void* const* d_in, const int* in_sizes, int n_in,
                              void* d_out, int out_size, void* d_ws, size_t ws_size,
                              hipStream_t stream) {
  int idx_f0 = -1, idx_f1 = -1, idx_rbf = -1, idx_rhat = -1, idx_mask = -1;
  int wa_i[4], ba_i[4], wb_i[4], bb_i[4], g_i[4];
  int nwa = 0, nba = 0, nwb = 0, nbb = 0, ng = 0;
  for (int k = 0; k < n_in; ++k) {
    const int s = in_sizes[k];
    if      (s == 4194304) idx_rbf  = k;
    else if (s == 786432)  idx_rhat = k;
    else if (s == 262144)  idx_mask = k;
    else if (s == 24576)   idx_f1   = k;
    else if (s == 8192)    { if (idx_f0 < 0) idx_f0 = k; else if (nwb < 4) wb_i[nwb++] = k; }
    else if (s == 512)     { if (nwa < 4) wa_i[nwa++] = k; }
    else if (s == 32)      { if (nba < 4) ba_i[nba++] = k; }
    else if (s == 256)     { if (nbb < 4) bb_i[nbb++] = k; }
    else if (s == 16)      { if (ng  < 4) g_i[ng++]  = k; }
  }
  const bool ok = idx_f0 >= 0 && idx_f1 >= 0 && idx_rbf >= 0 && idx_rhat >= 0 &&
                  idx_mask >= 0 && nwa == 4 && nba == 4 && nwb == 4 && nbb == 4 && ng == 4;
  if (!ok) {
    idx_f0 = 1; idx_f1 = 2; idx_rbf = 3; idx_rhat = 4; idx_mask = 5;
    for (int q = 0; q < 4; ++q) {
      wa_i[q] = 6 + q*4; ba_i[q] = 7 + q*4; wb_i[q] = 8 + q*4; bb_i[q] = 9 + q*4;
      g_i[q] = 22 + q;
    }
  }
  tfn_kernel<<<512, 256, 0, stream>>>(
      (const float*)d_in[idx_f0],  (const float*)d_in[idx_f1],
      (const float*)d_in[idx_rbf], (const float*)d_in[idx_rhat],
      (const int*)d_in[idx_mask],
      (const float*)d_in[wa_i[0]], (const float*)d_in[ba_i[0]],
      (const float*)d_in[wb_i[0]], (const float*)d_in[bb_i[0]],
      (const float*)d_in[wa_i[1]], (const float*)d_in[ba_i[1]],
      (const float*)d_in[wb_i[1]], (const float*)d_in[bb_i[1]],
      (const float*)d_in[wa_i[2]], (const float*)d_in[ba_i[2]],
      (const float*)d_in[wb_i[2]], (const float*)d_in[bb_i[2]],
      (const float*)d_in[wa_i[3]], (const float*)d_in[ba_i[3]],
      (const float*)d_in[wb_i[3]], (const float*)d_in[bb_i[3]],
      (const float*)d_in[g_i[0]], (const float*)d_in[g_i[1]],
      (const float*)d_in[g_i[2]], (const float*)d_in[g_i[3]],
      (float*)d_out);
}

// Round 13
// 200.065 us; speedup vs baseline: 1.3689x; 1.2996x over previous
//
#include <hip/hip_runtime.h>
#include <hip/hip_bf16.h>

#define NTOK 512
#define TJ 32
#define NTILE (NTOK/TJ)
#define EPSF 1e-5f

typedef __attribute__((ext_vector_type(4))) float f32x4;
typedef __attribute__((ext_vector_type(8))) short bf16x8;
typedef __attribute__((ext_vector_type(4))) short bf16x4;

struct HL { short hi; short lo; };

__device__ __forceinline__ short f2bf(float x) {
  __hip_bfloat16 h = __float2bfloat16(x);
  return *reinterpret_cast<short*>(&h);
}
__device__ __forceinline__ float bf2f(short s) {
  unsigned int u = ((unsigned int)(unsigned short)s) << 16;
  return __uint_as_float(u);
}
// split x ~= hi + lo (hi RNE bf16, lo = bf16(x - hi)): ~17 mantissa bits combined
__device__ __forceinline__ HL splitbf(float x) {
  HL r;
  r.hi = f2bf(x);
  r.lo = f2bf(x - bf2f(r.hi));
  return r;
}

// One block per i, 256 threads = 4 waves. 3xBF16 split-precision MFMA.
// Phase A: H[32j][128h] = silu(RBF[32][16] * WA^T[16][128] + ba), K 16->32 pad.
// Phase B: ACC[128m][32h-in-group] += LHS^T * H (4 block-diagonal GEMMs), K=32.
__global__ __launch_bounds__(256, 2) void tfn_kernel(
    const float* __restrict__ f0,  const float* __restrict__ f1,
    const float* __restrict__ rbf, const float* __restrict__ rhat,
    const int*  __restrict__ mask,
    const float* __restrict__ w00a, const float* __restrict__ b00a,
    const float* __restrict__ w00b, const float* __restrict__ b00b,
    const float* __restrict__ w10a, const float* __restrict__ b10a,
    const float* __restrict__ w10b, const float* __restrict__ b10b,
    const float* __restrict__ w01a, const float* __restrict__ b01a,
    const float* __restrict__ w01b, const float* __restrict__ b01b,
    const float* __restrict__ w11a, const float* __restrict__ b11a,
    const float* __restrict__ w11b, const float* __restrict__ b11b,
    const float* __restrict__ g0, const float* __restrict__ be0,
    const float* __restrict__ g1, const float* __restrict__ be1,
    float* __restrict__ out)
{
  __shared__ float f0s[32*20];
  __shared__ float f1s[32*52];
  __shared__ float rhs_s[96];
  __shared__ float maskf[32];
  __shared__ __align__(16) short Hh_s[128*40];  // [h][j] bf16 hi, stride 40
  __shared__ __align__(16) short Hl_s[128*40];  // lo
  __shared__ __align__(16) short Lh_s[128*40];  // [m][j] bf16 hi
  __shared__ __align__(16) short Ll_s[128*40];  // lo
  __shared__ float ACCs[128*33];
  __shared__ float biasL[256];
  __shared__ float m00s[16], m10s[16], p01s[48], p11s[48], rawbs[48], nrms[16];

  const int i = blockIdx.x;
  const int t = threadIdx.x;
  const int w = t >> 6;
  const int lane = t & 63;
  const int col = lane & 15;
  const int quad = lane >> 4;

  // ---- preload WA B-fragments (hi/lo) + ba for this wave's two h-tiles ----
  const int hn0 = 2*w, hn1 = 2*w + 1;
  bf16x8 bw0h = {0,0,0,0,0,0,0,0}, bw0l = {0,0,0,0,0,0,0,0};
  bf16x8 bw1h = {0,0,0,0,0,0,0,0}, bw1l = {0,0,0,0,0,0,0,0};
  float ba0v, ba1v;
  {
    const int h0 = hn0*16 + col, h1 = hn1*16 + col;
    const float* r0 = (h0 < 32) ? (w00a + h0*16) : (h0 < 64) ? (w10a + (h0-32)*16)
                    : (h0 < 96) ? (w01a + (h0-64)*16) : (w11a + (h0-96)*16);
    const float* r1 = (h1 < 32) ? (w00a + h1*16) : (h1 < 64) ? (w10a + (h1-32)*16)
                    : (h1 < 96) ? (w01a + (h1-64)*16) : (w11a + (h1-96)*16);
    ba0v = (h0 < 32) ? b00a[h0] : (h0 < 64) ? b10a[h0-32] : (h0 < 96) ? b01a[h0-64] : b11a[h0-96];
    ba1v = (h1 < 32) ? b00a[h1] : (h1 < 64) ? b10a[h1-32] : (h1 < 96) ? b01a[h1-64] : b11a[h1-96];
    if (quad < 2) {
      #pragma unroll
      for (int e = 0; e < 8; ++e) {
        HL s0 = splitbf(r0[quad*8 + e]); bw0h[e] = s0.hi; bw0l[e] = s0.lo;
        HL s1 = splitbf(r1[quad*8 + e]); bw1h[e] = s1.hi; bw1l[e] = s1.lo;
      }
    }
  }

  // ---- prefetch tile 0 (staging + rbf A-frags) into regs ----
  float4 pfA, pfB, pfC, pfD; int4 pfE;
  float4 cr00, cr01, cr10, cr11;
  {
    const int j0n = 0;
    if (t < 128) pfA = *(const float4*)(f0 + (j0n + (t>>2))*16 + (t&3)*4);
    { const int jj = t/12, e = t%12; pfB = *(const float4*)(f1 + (j0n + jj)*48 + e*4); }
    if (t < 128) { const int q2 = t+256, jj = q2/12, e = q2%12; pfC = *(const float4*)(f1 + (j0n + jj)*48 + e*4); }
    if (t < 24) pfD = *(const float4*)(rhat + ((size_t)i*NTOK + j0n)*3 + t*4);
    if (t < 8)  pfE = *(const int4*)(mask + (size_t)i*NTOK + j0n + t*4);
    if (quad < 2) {
      const float* pr = rbf + ((size_t)i*NTOK + j0n + col)*16 + quad*8;
      cr00 = *(const float4*)pr;         cr01 = *(const float4*)(pr+4);
      cr10 = *(const float4*)(pr+256);   cr11 = *(const float4*)(pr+260);
    }
  }

  f32x4 acc[4] = {{0.f,0.f,0.f,0.f},{0.f,0.f,0.f,0.f},{0.f,0.f,0.f,0.f},{0.f,0.f,0.f,0.f}};
  float biasp = 0.f;
  const f32x4 zc = {0.f,0.f,0.f,0.f};

  for (int tile = 0; tile < NTILE; ++tile) {
    // ---- S: write staged regs -> LDS ----
    if (t < 128) *(float4*)&f0s[(t>>2)*20 + (t&3)*4] = pfA;
    { const int jj = t/12, e = t%12; *(float4*)&f1s[jj*52 + e*4] = pfB; }
    if (t < 128) { const int q2 = t+256, jj = q2/12, e = q2%12; *(float4*)&f1s[jj*52 + e*4] = pfC; }
    if (t < 24) *(float4*)&rhs_s[t*4] = pfD;
    if (t < 8) {
      maskf[t*4+0] = pfE.x ? 1.f : 0.f; maskf[t*4+1] = pfE.y ? 1.f : 0.f;
      maskf[t*4+2] = pfE.z ? 1.f : 0.f; maskf[t*4+3] = pfE.w ? 1.f : 0.f;
    }
    __syncthreads();   // staging visible; H/L free (all threads past previous phase B)

    // ---- build phase-A A-frags (hi/lo) from current rbf regs ----
    bf16x8 a0h = {0,0,0,0,0,0,0,0}, a0l = {0,0,0,0,0,0,0,0};
    bf16x8 a1h = {0,0,0,0,0,0,0,0}, a1l = {0,0,0,0,0,0,0,0};
    if (quad < 2) {
      const float v0[8] = {cr00.x,cr00.y,cr00.z,cr00.w,cr01.x,cr01.y,cr01.z,cr01.w};
      const float v1[8] = {cr10.x,cr10.y,cr10.z,cr10.w,cr11.x,cr11.y,cr11.z,cr11.w};
      #pragma unroll
      for (int e = 0; e < 8; ++e) {
        HL s0 = splitbf(v0[e]); a0h[e] = s0.hi; a0l[e] = s0.lo;
        HL s1 = splitbf(v1[e]); a1h[e] = s1.hi; a1l[e] = s1.lo;
      }
    }

    // ---- lhs: fp32 compute -> hi/lo bf16 -> Lh/Ll; fp32 bias accumulate ----
    {
      const int m = t >> 1, jh = t & 1;
      float vals[16]; float bsum = 0.f;
      #pragma unroll
      for (int jj = 0; jj < 16; ++jj) {
        const int j = jh*16 + jj;
        const float mk = maskf[j];
        float v;
        if (m < 16)       v = mk * f0s[j*20 + m];
        else if (m < 32)  { const int c = m-16;
          v = mk * (rhs_s[j*3+0]*f1s[j*52+c*3+0] + rhs_s[j*3+1]*f1s[j*52+c*3+1] + rhs_s[j*3+2]*f1s[j*52+c*3+2]); }
        else if (m < 80)  { const int mm = m-32, f = mm/3, x = mm%3; v = mk * f0s[j*20+f] * rhs_s[j*3+x]; }
        else              v = mk * f1s[j*52 + (m-80)];
        vals[jj] = v; bsum += v;
      }
      biasp += bsum;
      #pragma unroll
      for (int q = 0; q < 4; ++q) {
        bf16x4 ph, pl;
        #pragma unroll
        for (int r = 0; r < 4; ++r) { HL s = splitbf(vals[q*4+r]); ph[r] = s.hi; pl[r] = s.lo; }
        *(bf16x4*)&Lh_s[m*40 + jh*16 + q*4] = ph;
        *(bf16x4*)&Ll_s[m*40 + jh*16 + q*4] = pl;
      }
    }

    // ---- prefetch tile+1 into regs ----
    if (tile + 1 < NTILE) {
      const int j0n = (tile+1)*TJ;
      if (t < 128) pfA = *(const float4*)(f0 + (j0n + (t>>2))*16 + (t&3)*4);
      { const int jj = t/12, e = t%12; pfB = *(const float4*)(f1 + (j0n + jj)*48 + e*4); }
      if (t < 128) { const int q2 = t+256, jj = q2/12, e = q2%12; pfC = *(const float4*)(f1 + (j0n + jj)*48 + e*4); }
      if (t < 24) pfD = *(const float4*)(rhat + ((size_t)i*NTOK + j0n)*3 + t*4);
      if (t < 8)  pfE = *(const int4*)(mask + (size_t)i*NTOK + j0n + t*4);
      if (quad < 2) {
        const float* pr = rbf + ((size_t)i*NTOK + j0n + col)*16 + quad*8;
        cr00 = *(const float4*)pr;       cr01 = *(const float4*)(pr+4);
        cr10 = *(const float4*)(pr+256); cr11 = *(const float4*)(pr+260);
      }
    }

    // ---- phase A: 3xBF16 MFMA + silu -> Hh/Hl ----
    {
      f32x4 d00 = __builtin_amdgcn_mfma_f32_16x16x32_bf16(a0l, bw0h, zc, 0, 0, 0);
      d00 = __builtin_amdgcn_mfma_f32_16x16x32_bf16(a0h, bw0l, d00, 0, 0, 0);
      d00 = __builtin_amdgcn_mfma_f32_16x16x32_bf16(a0h, bw0h, d00, 0, 0, 0);
      f32x4 d01 = __builtin_amdgcn_mfma_f32_16x16x32_bf16(a0l, bw1h, zc, 0, 0, 0);
      d01 = __builtin_amdgcn_mfma_f32_16x16x32_bf16(a0h, bw1l, d01, 0, 0, 0);
      d01 = __builtin_amdgcn_mfma_f32_16x16x32_bf16(a0h, bw1h, d01, 0, 0, 0);
      f32x4 d10 = __builtin_amdgcn_mfma_f32_16x16x32_bf16(a1l, bw0h, zc, 0, 0, 0);
      d10 = __builtin_amdgcn_mfma_f32_16x16x32_bf16(a1h, bw0l, d10, 0, 0, 0);
      d10 = __builtin_amdgcn_mfma_f32_16x16x32_bf16(a1h, bw0h, d10, 0, 0, 0);
      f32x4 d11 = __builtin_amdgcn_mfma_f32_16x16x32_bf16(a1l, bw1h, zc, 0, 0, 0);
      d11 = __builtin_amdgcn_mfma_f32_16x16x32_bf16(a1h, bw1l, d11, 0, 0, 0);
      d11 = __builtin_amdgcn_mfma_f32_16x16x32_bf16(a1h, bw1h, d11, 0, 0, 0);
      bf16x4 hv, lv;
      #pragma unroll
      for (int r = 0; r < 4; ++r) { float p = d00[r] + ba0v; float s = p / (1.f + __expf(-p)); HL e = splitbf(s); hv[r] = e.hi; lv[r] = e.lo; }
      *(bf16x4*)&Hh_s[(hn0*16+col)*40 + 0*16 + quad*4] = hv;
      *(bf16x4*)&Hl_s[(hn0*16+col)*40 + 0*16 + quad*4] = lv;
      #pragma unroll
      for (int r = 0; r < 4; ++r) { float p = d01[r] + ba1v; float s = p / (1.f + __expf(-p)); HL e = splitbf(s); hv[r] = e.hi; lv[r] = e.lo; }
      *(bf16x4*)&Hh_s[(hn1*16+col)*40 + 0*16 + quad*4] = hv;
      *(bf16x4*)&Hl_s[(hn1*16+col)*40 + 0*16 + quad*4] = lv;
      #pragma unroll
      for (int r = 0; r < 4; ++r) { float p = d10[r] + ba0v; float s = p / (1.f + __expf(-p)); HL e = splitbf(s); hv[r] = e.hi; lv[r] = e.lo; }
      *(bf16x4*)&Hh_s[(hn0*16+col)*40 + 1*16 + quad*4] = hv;
      *(bf16x4*)&Hl_s[(hn0*16+col)*40 + 1*16 + quad*4] = lv;
      #pragma unroll
      for (int r = 0; r < 4; ++r) { float p = d11[r] + ba1v; float s = p / (1.f + __expf(-p)); HL e = splitbf(s); hv[r] = e.hi; lv[r] = e.lo; }
      *(bf16x4*)&Hh_s[(hn1*16+col)*40 + 1*16 + quad*4] = hv;
      *(bf16x4*)&Hl_s[(hn1*16+col)*40 + 1*16 + quad*4] = lv;
    }
    __syncthreads();   // H/L visible; staging fully consumed

    // ---- phase B: 3xBF16 MFMA: ACC += LHS^T * H ----
    #pragma unroll
    for (int k = 0; k < 4; ++k) {
      const int mt = 2*w + (k>>1);
      const int hn = (w==0) ? k : (w==1) ? (4+(k&1)) : (w==2) ? (4+k) : (6+(k&1));
      const bf16x8 afh = *(const bf16x8*)&Lh_s[(mt*16+col)*40 + quad*8];
      const bf16x8 afl = *(const bf16x8*)&Ll_s[(mt*16+col)*40 + quad*8];
      const bf16x8 bfh = *(const bf16x8*)&Hh_s[(hn*16+col)*40 + quad*8];
      const bf16x8 bfl = *(const bf16x8*)&Hl_s[(hn*16+col)*40 + quad*8];
      acc[k] = __builtin_amdgcn_mfma_f32_16x16x32_bf16(afl, bfh, acc[k], 0, 0, 0);
      acc[k] = __builtin_amdgcn_mfma_f32_16x16x32_bf16(afh, bfl, acc[k], 0, 0, 0);
      acc[k] = __builtin_amdgcn_mfma_f32_16x16x32_bf16(afh, bfh, acc[k], 0, 0, 0);
    }
  }

  // ---- dump ACC frags + bias partials ----
  #pragma unroll
  for (int k = 0; k < 4; ++k) {
    const int mt = 2*w + (k>>1);
    const int hn = (w==0) ? k : (w==1) ? (4+(k&1)) : (w==2) ? (4+k) : (6+(k&1));
    #pragma unroll
    for (int r = 0; r < 4; ++r)
      ACCs[(mt*16 + quad*4 + r)*33 + (hn&1)*16 + col] = acc[k][r];
  }
  biasL[t] = biasp;
  __syncthreads();

  // ---- epilogue: second-layer contraction + LN ----
  if (t < 16) {
    const int o = t; float s = 0.f;
    for (int d = 0; d < 16; ++d) {
      const float* wrow = w00b + (d*16 + o)*32;
      float ss = 0.f;
      #pragma unroll
      for (int h = 0; h < 32; ++h) ss += wrow[h] * ACCs[d*33 + h];
      s += ss + b00b[d*16 + o] * (biasL[2*d] + biasL[2*d+1]);
    }
    m00s[o] = s;
  } else if (t < 32) {
    const int o = t - 16; float s = 0.f;
    for (int c = 0; c < 16; ++c) {
      const float* wrow = w10b + (c*16 + o)*32;
      const int m = 16 + c;
      float ss = 0.f;
      #pragma unroll
      for (int h = 0; h < 32; ++h) ss += wrow[h] * ACCs[m*33 + h];
      s += ss + b10b[c*16 + o] * (biasL[2*m] + biasL[2*m+1]);
    }
    m10s[o] = s;
  } else if (t < 80) {
    const int idx = t - 32, g = idx/3, x = idx%3; float s = 0.f;
    for (int f = 0; f < 16; ++f) {
      const float* wrow = w01b + (f*16 + g)*32;
      const int m = 32 + f*3 + x;
      float ss = 0.f;
      #pragma unroll
      for (int h = 0; h < 32; ++h) ss += wrow[h] * ACCs[m*33 + h];
      s += ss + b01b[f*16 + g] * (biasL[2*m] + biasL[2*m+1]);
    }
    p01s[idx] = s;
  } else if (t < 128) {
    const int idx = t - 80, g = idx/3, x = idx%3; float s = 0.f;
    for (int k = 0; k < 16; ++k) {
      const float* wrow = w11b + (k*16 + g)*32;
      const int m = 80 + k*3 + x;
      float ss = 0.f;
      #pragma unroll
      for (int h = 0; h < 32; ++h) ss += wrow[h] * ACCs[m*33 + h];
      s += ss + b11b[k*16 + g] * (biasL[2*m] + biasL[2*m+1]);
    }
    p11s[idx] = s;
  }
  __syncthreads();

  if (t < 16) {
    float v = m00s[t] + m10s[t];
    float mu = 0.f;
    #pragma unroll
    for (int k = 0; k < 16; ++k) mu += m00s[k] + m10s[k];
    mu *= (1.f/16.f);
    float var = 0.f;
    #pragma unroll
    for (int k = 0; k < 16; ++k) { float d = m00s[k] + m10s[k] - mu; var += d*d; }
    var *= (1.f/16.f);
    out[(size_t)i*16 + t] = (v - mu) * rsqrtf(var + EPSF) * g0[t] + be0[t];
    float r0v = p01s[t*3+0] + p11s[t*3+0];
    float r1v = p01s[t*3+1] + p11s[t*3+1];
    float r2v = p01s[t*3+2] + p11s[t*3+2];
    rawbs[t*3+0] = r0v; rawbs[t*3+1] = r1v; rawbs[t*3+2] = r2v;
    nrms[t] = fmaxf(sqrtf(r0v*r0v + r1v*r1v + r2v*r2v), 1e-8f);
  }
  __syncthreads();
  if (t < 16) {
    float mu = 0.f;
    #pragma unroll
    for (int k = 0; k < 16; ++k) mu += nrms[k];
    mu *= (1.f/16.f);
    float var = 0.f;
    #pragma unroll
    for (int k = 0; k < 16; ++k) { float d = nrms[k] - mu; var += d*d; }
    var *= (1.f/16.f);
    const float ln = (nrms[t] - mu) * rsqrtf(var + EPSF) * g1[t] + be1[t];
    const float scale = ln / nrms[t];
    const size_t base = (size_t)NTOK*16 + (size_t)i*48 + t*3;
    out[base+0] = rawbs[t*3+0] * scale;
    out[base+1] = rawbs[t*3+1] * scale;
    out[base+2] = rawbs[t*3+2] * scale;
  }
}

extern "C" void kernel_launch(void* const* d_in, const int* in_sizes, int n_in,
                              void* d_out, int out_size, void* d_ws, size_t ws_size,
                              hipStream_t stream) {
  int idx_f0 = -1, idx_f1 = -1, idx_rbf = -1, idx_rhat = -1, idx_mask = -1;
  int wa_i[4], ba_i[4], wb_i[4], bb_i[4], g_i[4];
  int nwa = 0, nba = 0, nwb = 0, nbb = 0, ng = 0;
  for (int k = 0; k < n_in; ++k) {
    const int s = in_sizes[k];
    if      (s == 4194304) idx_rbf  = k;
    else if (s == 786432)  idx_rhat = k;
    else if (s == 262144)  idx_mask = k;
    else if (s == 24576)   idx_f1   = k;
    else if (s == 8192)    { if (idx_f0 < 0) idx_f0 = k; else if (nwb < 4) wb_i[nwb++] = k; }
    else if (s == 512)     { if (nwa < 4) wa_i[nwa++] = k; }
    else if (s == 32)      { if (nba < 4) ba_i[nba++] = k; }
    else if (s == 256)     { if (nbb < 4) bb_i[nbb++] = k; }
    else if (s == 16)      { if (ng  < 4) g_i[ng++]  = k; }
  }
  const bool ok = idx_f0 >= 0 && idx_f1 >= 0 && idx_rbf >= 0 && idx_rhat >= 0 &&
                  idx_mask >= 0 && nwa == 4 && nba == 4 && nwb == 4 && nbb == 4 && ng == 4;
  if (!ok) {
    idx_f0 = 1; idx_f1 = 2; idx_rbf = 3; idx_rhat = 4; idx_mask = 5;
    for (int q = 0; q < 4; ++q) {
      wa_i[q] = 6 + q*4; ba_i[q] = 7 + q*4; wb_i[q] = 8 + q*4; bb_i[q] = 9 + q*4;
      g_i[q] = 22 + q;
    }
  }
  tfn_kernel<<<512, 256, 0, stream>>>(
      (const float*)d_in[idx_f0],  (const float*)d_in[idx_f1],
      (const float*)d_in[idx_rbf], (const float*)d_in[idx_rhat],
      (const int*)d_in[idx_mask],
      (const float*)d_in[wa_i[0]], (const float*)d_in[ba_i[0]],
      (const float*)d_in[wb_i[0]], (const float*)d_in[bb_i[0]],
      (const float*)d_in[wa_i[1]], (const float*)d_in[ba_i[1]],
      (const float*)d_in[wb_i[1]], (const float*)d_in[bb_i[1]],
      (const float*)d_in[wa_i[2]], (const float*)d_in[ba_i[2]],
      (const float*)d_in[wb_i[2]], (const float*)d_in[bb_i[2]],
      (const float*)d_in[wa_i[3]], (const float*)d_in[ba_i[3]],
      (const float*)d_in[wb_i[3]], (const float*)d_in[bb_i[3]],
      (const float*)d_in[g_i[0]], (const float*)d_in[g_i[1]],
      (const float*)d_in[g_i[2]], (const float*)d_in[g_i[3]],
      (float*)d_out);
}